// Round 1
// baseline (2850.719 us; speedup 1.0000x reference)
//
#include <hip/hip_runtime.h>

// PNA GNN (2 layers) on MI355X — fp32 baseline, gather-fused tiled GEMMs.
// Sizes fixed by the problem:
#define NODES 10000
#define EDGES 160000
#define FDIM 64
#define DDIM 32
#define HDIM 128
#define AVG_DEG_LOG 2.8332133440562162f   // log(17)
#define EPS_BN 1e-5f
#define EPS_STD 1e-5f

// ---------------------------------------------------------------------------
// Generic tiled GEMM: C[M,128] = gatherA[M,K] @ B[K,128] + bias, epilogues.
// BM=64, BN=64, BK=16, 256 threads, 4x4 micro-tile per thread.
// AMODE 0: A direct [M,K]
// AMODE 1: cat3  — k<128: s0[i0[r]*128+k]; k<256: s1[i1[r]*128+k-128]; else A[r*128+k-256]
// AMODE 2: post  — k<128: A(=xh)[r*128+k]; else agg[r*512 + (k-128)%512] * {1,f,1/f}[(k-128)/512]
// EPI 0: C = acc+bias   EPI 1: relu   EPI 2: C += 0.5*(acc+bias)  (in-place)
// ---------------------------------------------------------------------------
struct GArgs {
  const float* A;
  const float* s0;
  const float* s1;
  const int*   i0;
  const int*   i1;
  const float* agg;
  const float* fs;
  const float* invfs;
  const float* B;
  const float* bias;
  float*       C;
  int M, K;
};

template<int AMODE>
__device__ __forceinline__ float fetchA(const GArgs& g, int r, int k){
  if constexpr (AMODE == 0) {
    return g.A[r * g.K + k];
  } else if constexpr (AMODE == 1) {
    if (k < HDIM)        return g.s0[g.i0[r] * HDIM + k];
    else if (k < 2*HDIM) return g.s1[g.i1[r] * HDIM + (k - HDIM)];
    else                 return g.A[r * HDIM + (k - 2*HDIM)];
  } else {
    if (k < HDIM) return g.A[r * HDIM + k];
    int q = k - HDIM; int seg = q >> 9; int kk = q & 511;
    float v = g.agg[r * 512 + kk];
    if (seg == 1)      v *= g.fs[r];
    else if (seg == 2) v *= g.invfs[r];
    return v;
  }
}

template<int AMODE, int EPI>
__global__ __launch_bounds__(256) void gemm_k(GArgs g){
  __shared__ float As[16][68];   // +4 pad: float4-aligned rows, conflict-light
  __shared__ float Bs[16][68];
  const int tid = threadIdx.x;
  const int tx = tid & 15, ty = tid >> 4;
  const int row0 = blockIdx.y * 64, col0 = blockIdx.x * 64;
  float acc[4][4] = {};

  for (int k0 = 0; k0 < g.K; k0 += 16){
    #pragma unroll
    for (int i = 0; i < 4; i++){
      int l = tid + i * 256;
      int ar = l >> 4, ak = l & 15;
      int gr = row0 + ar;
      float v = 0.f;
      if (gr < g.M) v = fetchA<AMODE>(g, gr, k0 + ak);
      As[ak][ar] = v;
    }
    #pragma unroll
    for (int i = 0; i < 4; i++){
      int l = tid + i * 256;
      int bn_ = l & 63, bk = l >> 6;
      Bs[bk][bn_] = g.B[(k0 + bk) * HDIM + col0 + bn_];
    }
    __syncthreads();
    #pragma unroll
    for (int kk = 0; kk < 16; kk++){
      float a[4], b[4];
      #pragma unroll
      for (int j = 0; j < 4; j++) a[j] = As[kk][ty*4 + j];
      #pragma unroll
      for (int j = 0; j < 4; j++) b[j] = Bs[kk][tx*4 + j];
      #pragma unroll
      for (int ii = 0; ii < 4; ii++)
        #pragma unroll
        for (int jj = 0; jj < 4; jj++)
          acc[ii][jj] = fmaf(a[ii], b[jj], acc[ii][jj]);
    }
    __syncthreads();
  }

  #pragma unroll
  for (int ii = 0; ii < 4; ii++){
    int gr = row0 + ty*4 + ii;
    if (gr >= g.M) continue;
    #pragma unroll
    for (int jj = 0; jj < 4; jj++){
      int gc = col0 + tx*4 + jj;
      float v = acc[ii][jj] + g.bias[gc];
      if constexpr (EPI == 1) v = fmaxf(v, 0.f);
      float* cp = g.C + gr * HDIM + gc;
      if constexpr (EPI == 2) v = *cp + 0.5f * v;
      *cp = v;
    }
  }
}

// ---------------------------------------------------------------------------
// Multi-aggregator scatter (mean/min/max/std at dst) via L2 atomics.
// Monotonic uint mapping for float atomic min/max.
// ---------------------------------------------------------------------------
__device__ __forceinline__ unsigned fmap(float x){
  unsigned u = __float_as_uint(x);
  return (u & 0x80000000u) ? ~u : (u | 0x80000000u);
}
__device__ __forceinline__ float funmap(unsigned m){
  unsigned u = (m & 0x80000000u) ? (m & 0x7FFFFFFFu) : ~m;
  return __uint_as_float(u);
}

__global__ void init_agg_k(float* sum, float* sumsq, unsigned* minb, unsigned* maxb, int* cnt){
  int i = blockIdx.x * 256 + threadIdx.x;
  if (i < NODES * HDIM){
    sum[i] = 0.f; sumsq[i] = 0.f;
    minb[i] = 0xFFFFFFFFu; maxb[i] = 0u;
  }
  if (i < NODES) cnt[i] = 0;
}

__global__ void scatter_k(const float* __restrict__ h, const int* __restrict__ dst,
                          float* sum, float* sumsq, unsigned* minb, unsigned* maxb, int* cnt){
  int i = blockIdx.x * 256 + threadIdx.x;
  if (i >= EDGES * HDIM) return;
  int e = i >> 7, c = i & 127;
  int d = dst[e];
  float v = h[i];
  int o = d * HDIM + c;
  atomicAdd(&sum[o], v);
  atomicAdd(&sumsq[o], v * v);
  unsigned m = fmap(v);
  atomicMax(&maxb[o], m);
  atomicMin(&minb[o], m);
  if (c == 0) atomicAdd(&cnt[d], 1);
}

__global__ void finalize_k(const float* __restrict__ sum, const float* __restrict__ sumsq,
                           const unsigned* __restrict__ minb, const unsigned* __restrict__ maxb,
                           const int* __restrict__ cnt,
                           float* __restrict__ agg, float* __restrict__ fdeg, float* __restrict__ invf){
  int i = blockIdx.x * 256 + threadIdx.x;
  if (i >= NODES * HDIM) return;
  int n = i >> 7, c = i & 127;
  float cn = (float)cnt[n];
  float degc = fmaxf(cn, 1.f);
  float mean = sum[i] / degc;
  float msq  = sumsq[i] / degc;
  float var  = fmaxf(msq - mean * mean, 0.f);
  float sd   = sqrtf(var + EPS_STD);
  float mn = (cn > 0.f) ? funmap(minb[i]) : 0.f;
  float mx = (cn > 0.f) ? funmap(maxb[i]) : 0.f;
  float* a = agg + n * 512;
  a[c]       = mean;
  a[128 + c] = mn;
  a[256 + c] = mx;
  a[384 + c] = sd;
  if (c == 0){
    float ff = logf(degc + 1.f) / AVG_DEG_LOG;
    fdeg[n] = ff;
    invf[n] = 1.f / ff;
  }
}

// BatchNorm batch stats: one block per column (128 blocks), biased variance.
__global__ __launch_bounds__(256) void bn_stats_k(const float* __restrict__ out2, float* mu, float* var){
  __shared__ float sh1[256], sh2[256];
  int c = blockIdx.x;
  float s = 0.f, ss = 0.f;
  for (int r = threadIdx.x; r < NODES; r += 256){
    float v = out2[r * HDIM + c];
    s += v; ss += v * v;
  }
  sh1[threadIdx.x] = s; sh2[threadIdx.x] = ss;
  __syncthreads();
  for (int o = 128; o > 0; o >>= 1){
    if (threadIdx.x < o){ sh1[threadIdx.x] += sh1[threadIdx.x + o]; sh2[threadIdx.x] += sh2[threadIdx.x + o]; }
    __syncthreads();
  }
  if (threadIdx.x == 0){
    float m = sh1[0] / (float)NODES;
    mu[c] = m;
    var[c] = sh2[0] / (float)NODES - m * m;
  }
}

__global__ void xh_update_k(float* __restrict__ xh, const float* __restrict__ out2,
                            const float* __restrict__ mu, const float* __restrict__ var,
                            const float* __restrict__ gamma, const float* __restrict__ beta){
  int i = blockIdx.x * 256 + threadIdx.x;
  if (i >= NODES * HDIM) return;
  int c = i & 127;
  float bn = gamma[c] * (out2[i] - mu[c]) * rsqrtf(var[c] + EPS_BN) + beta[c];
  xh[i] = (xh[i] + fmaxf(bn, 0.f)) * 0.5f;
}

// ---------------------------------------------------------------------------
extern "C" void kernel_launch(void* const* d_in, const int* in_sizes, int n_in,
                              void* d_out, int out_size, void* d_ws, size_t ws_size,
                              hipStream_t stream) {
  const float* x      = (const float*)d_in[0];
  const int*   ei     = (const int*)  d_in[1];
  const float* ea     = (const float*)d_in[2];
  const float* W_node = (const float*)d_in[3];
  const float* b_node = (const float*)d_in[4];
  const float* W_edge = (const float*)d_in[5];
  const float* b_edge = (const float*)d_in[6];
  const float* W_ee   = (const float*)d_in[7];
  const float* b_ee   = (const float*)d_in[8];
  const float* W_pre  = (const float*)d_in[9];
  const float* b_pre  = (const float*)d_in[10];
  const float* W_post = (const float*)d_in[11];
  const float* b_post = (const float*)d_in[12];
  const float* W_lin  = (const float*)d_in[13];
  const float* b_lin  = (const float*)d_in[14];
  const float* gamma  = (const float*)d_in[15];
  const float* beta   = (const float*)d_in[16];
  const float* We1    = (const float*)d_in[17];
  const float* be1    = (const float*)d_in[18];
  const float* We2    = (const float*)d_in[19];
  const float* be2    = (const float*)d_in[20];

  const int* src = ei;
  const int* dst = ei + EDGES;

  // Outputs live directly in d_out: xh [N,128] then e [E,128].
  float* xh = (float*)d_out;
  float* e  = xh + NODES * HDIM;

  // Workspace layout (floats).
  float* ws    = (float*)d_ws;
  float* e_enc = ws;                                  // E*128
  float* h     = e_enc + EDGES * HDIM;                // E*128 (reused as t1)
  float* agg   = h + EDGES * HDIM;                    // N*512
  float* sum   = agg + NODES * 512;                   // N*128
  float* sumsq = sum + NODES * HDIM;                  // N*128
  unsigned* minb = (unsigned*)(sumsq + NODES * HDIM); // N*128
  unsigned* maxb = minb + NODES * HDIM;               // N*128
  int*   cnt  = (int*)(maxb + NODES * HDIM);          // N
  float* fdeg = (float*)(cnt + NODES);                // N
  float* invf = fdeg + NODES;                         // N
  float* out1 = invf + NODES;                         // N*128
  float* out2 = out1 + NODES * HDIM;                  // N*128
  float* mu   = out2 + NODES * HDIM;                  // 128
  float* var  = mu + HDIM;                            // 128

  dim3 blk(256);
  auto gemm_grid = [](int M){ return dim3(2, (M + 63) / 64); };

  GArgs g{};

  // xh = x @ W_node + b_node
  g = GArgs{ x, nullptr, nullptr, nullptr, nullptr, nullptr, nullptr, nullptr,
             W_node, b_node, xh, NODES, FDIM };
  gemm_k<0,0><<<gemm_grid(NODES), blk, 0, stream>>>(g);

  // e = edge_attr @ W_edge + b_edge
  g = GArgs{ ea, nullptr, nullptr, nullptr, nullptr, nullptr, nullptr, nullptr,
             W_edge, b_edge, e, EDGES, DDIM };
  gemm_k<0,0><<<gemm_grid(EDGES), blk, 0, stream>>>(g);

  for (int l = 0; l < 2; l++){
    const float* W_ee_l   = W_ee   + l * HDIM * HDIM;
    const float* b_ee_l   = b_ee   + l * HDIM;
    const float* W_pre_l  = W_pre  + l * 3 * HDIM * HDIM;
    const float* b_pre_l  = b_pre  + l * HDIM;
    const float* W_post_l = W_post + l * 13 * HDIM * HDIM;
    const float* b_post_l = b_post + l * HDIM;
    const float* W_lin_l  = W_lin  + l * HDIM * HDIM;
    const float* b_lin_l  = b_lin  + l * HDIM;
    const float* gamma_l  = gamma  + l * HDIM;
    const float* beta_l   = beta   + l * HDIM;
    const float* We1_l    = We1    + l * 3 * HDIM * HDIM;
    const float* be1_l    = be1    + l * HDIM;
    const float* We2_l    = We2    + l * HDIM * HDIM;
    const float* be2_l    = be2    + l * HDIM;

    // e_enc = e @ W_ee + b_ee
    g = GArgs{ e, nullptr, nullptr, nullptr, nullptr, nullptr, nullptr, nullptr,
               W_ee_l, b_ee_l, e_enc, EDGES, HDIM };
    gemm_k<0,0><<<gemm_grid(EDGES), blk, 0, stream>>>(g);

    // h = [xh[dst], xh[src], e_enc] @ W_pre + b_pre
    g = GArgs{ e_enc, xh, xh, dst, src, nullptr, nullptr, nullptr,
               W_pre_l, b_pre_l, h, EDGES, 3 * HDIM };
    gemm_k<1,0><<<gemm_grid(EDGES), blk, 0, stream>>>(g);

    // multi-aggregator scatter at dst
    init_agg_k<<<(NODES * HDIM + 255) / 256, blk, 0, stream>>>(sum, sumsq, minb, maxb, cnt);
    scatter_k<<<(EDGES * HDIM + 255) / 256, blk, 0, stream>>>(h, dst, sum, sumsq, minb, maxb, cnt);
    finalize_k<<<(NODES * HDIM + 255) / 256, blk, 0, stream>>>(sum, sumsq, minb, maxb, cnt, agg, fdeg, invf);

    // out1 = [xh, agg, agg*f, agg/f] @ W_post + b_post
    g = GArgs{ xh, nullptr, nullptr, nullptr, nullptr, agg, fdeg, invf,
               W_post_l, b_post_l, out1, NODES, 13 * HDIM };
    gemm_k<2,0><<<gemm_grid(NODES), blk, 0, stream>>>(g);

    // out2 = out1 @ W_lin + b_lin
    g = GArgs{ out1, nullptr, nullptr, nullptr, nullptr, nullptr, nullptr, nullptr,
               W_lin_l, b_lin_l, out2, NODES, HDIM };
    gemm_k<0,0><<<gemm_grid(NODES), blk, 0, stream>>>(g);

    // BatchNorm + residual relu
    bn_stats_k<<<HDIM, blk, 0, stream>>>(out2, mu, var);
    xh_update_k<<<(NODES * HDIM + 255) / 256, blk, 0, stream>>>(xh, out2, mu, var, gamma_l, beta_l);

    // t1 = relu([xh[src], xh[dst], e] @ We1 + be1)   (t1 reuses h)
    g = GArgs{ e, xh, xh, src, dst, nullptr, nullptr, nullptr,
               We1_l, be1_l, h, EDGES, 3 * HDIM };
    gemm_k<1,1><<<gemm_grid(EDGES), blk, 0, stream>>>(g);

    // e += 0.5 * (t1 @ We2 + be2)   (in-place epilogue)
    g = GArgs{ h, nullptr, nullptr, nullptr, nullptr, nullptr, nullptr, nullptr,
               We2_l, be2_l, e, EDGES, HDIM };
    gemm_k<0,2><<<gemm_grid(EDGES), blk, 0, stream>>>(g);
  }
}

// Round 2
// 1387.947 us; speedup vs baseline: 2.0539x; 2.0539x over previous
//
#include <hip/hip_runtime.h>

// PNA GNN (2 layers) on MI355X — bf16x3 MFMA GEMMs + fused gathers.
#define NODES 10000
#define EDGES 160000
#define FDIM 64
#define DDIM 32
#define HDIM 128
#define AVG_DEG_LOG 2.8332133440562162f   // log(17)
#define EPS_BN 1e-5f
#define EPS_STD 1e-5f

typedef short bf16x8 __attribute__((ext_vector_type(8)));   // 8 bf16 (4 VGPRs)
typedef float f32x4  __attribute__((ext_vector_type(4)));   // 4 fp32

struct GArgs {
  const float* A;
  const float* s0;
  const float* s1;
  const int*   i0;
  const int*   i1;
  const float* agg;
  const float* fs;
  const float* invfs;
  const float* B;       // fp32 B for the small weight-combine GEMM
  const unsigned short* Bph;  // prepped bf16-hi fragments
  const unsigned short* Bpl;  // prepped bf16-lo fragments
  const float* bias;
  float*       C;
  int M, K;
};

// ---------------- bf16 helpers ----------------
__device__ __forceinline__ unsigned short f2bf(float x){
  unsigned u = __float_as_uint(x);
  return (unsigned short)((u + 0x7FFFu + ((u >> 16) & 1u)) >> 16);
}
__device__ __forceinline__ float bf2f(unsigned short h){
  return __uint_as_float(((unsigned)h) << 16);
}

// ===========================================================================
// MFMA GEMM: C[M,128] = gatherA[M,K] @ W[K,128] + bias, bf16x3 split.
// Block: 256 thr (4 waves), BM=128, BN=128, BK=32, double-buffered LDS.
// Wave w: row-half rh=w>>1 (64 rows = 4 frags), col-half ch=w&1 (4 frags).
// mfma_f32_16x16x32_bf16: A row=lane&15, k=(lane>>4)*8+i; B col=lane&15 same k.
// C/D: col=lane&15, row=(lane>>4)*4+reg (verified mapping).
// AMODE 0: direct [M,K]; 1: [s0[i0], s1[i1], A] (each 128 wide);
// AMODE 2: [A(128) | agg | agg*fs | agg*invfs] (agg 512 wide).
// EPI 0: store; 1: relu-store; 2: C += 0.5*(acc+bias).
// ===========================================================================
#define BK 32
#define APAD 8
#define ASTR (BK + APAD)   // 40 bf16 = 80 B row stride (2-way bank alias: free)

template<int AMODE>
__device__ __forceinline__ void stage_load(const GArgs& g, int row0, int k0, float4 (&v)[4]){
  const int tid = threadIdx.x;
  const int r  = tid >> 1;
  const int c0 = (tid & 1) << 4;      // 0 or 16 floats within the 32-wide tile
  const int gr = row0 + r;
  if (gr >= g.M){
    v[0] = v[1] = v[2] = v[3] = make_float4(0.f, 0.f, 0.f, 0.f);
    return;
  }
  const int kk = k0 + c0;
  const float* p;
  float scale = 1.f;
  if constexpr (AMODE == 0){
    p = g.A + (size_t)gr * g.K + kk;
  } else if constexpr (AMODE == 1){
    if (kk < HDIM)          p = g.s0 + (size_t)g.i0[gr] * HDIM + kk;
    else if (kk < 2*HDIM)   p = g.s1 + (size_t)g.i1[gr] * HDIM + (kk - HDIM);
    else                    p = g.A  + (size_t)gr * HDIM + (kk - 2*HDIM);
  } else {
    if (kk < HDIM){
      p = g.A + (size_t)gr * HDIM + kk;
    } else {
      int q = kk - HDIM; int seg = q >> 9;
      p = g.agg + (size_t)gr * 512 + (q & 511);
      if (seg == 1)      scale = g.fs[gr];
      else if (seg == 2) scale = g.invfs[gr];
    }
  }
  const float4* p4 = (const float4*)p;
  v[0] = p4[0]; v[1] = p4[1]; v[2] = p4[2]; v[3] = p4[3];
  if (scale != 1.f){
    #pragma unroll
    for (int j = 0; j < 4; j++){
      v[j].x *= scale; v[j].y *= scale; v[j].z *= scale; v[j].w *= scale;
    }
  }
}

__device__ __forceinline__ void stage_write(unsigned short* __restrict__ AhB,
                                            unsigned short* __restrict__ AlB,
                                            const float4 (&v)[4]){
  const int tid = threadIdx.x;
  const int base = (tid >> 1) * ASTR + ((tid & 1) << 4);
  #pragma unroll
  for (int j = 0; j < 4; j++){
    ushort4 h, l;
    h.x = f2bf(v[j].x); l.x = f2bf(v[j].x - bf2f(h.x));
    h.y = f2bf(v[j].y); l.y = f2bf(v[j].y - bf2f(h.y));
    h.z = f2bf(v[j].z); l.z = f2bf(v[j].z - bf2f(h.z));
    h.w = f2bf(v[j].w); l.w = f2bf(v[j].w - bf2f(h.w));
    *(ushort4*)&AhB[base + j*4] = h;
    *(ushort4*)&AlB[base + j*4] = l;
  }
}

template<int AMODE, int EPI>
__global__ __launch_bounds__(256) void mgemm_k(GArgs g){
  __shared__ unsigned short Ah[2][128 * ASTR];
  __shared__ unsigned short Al[2][128 * ASTR];
  const int tid  = threadIdx.x;
  const int row0 = blockIdx.y * 128;
  const int wave = tid >> 6, lane = tid & 63;
  const int rh = wave >> 1, ch = wave & 1;
  const int lrow = lane & 15, lk = lane >> 4;

  f32x4 acc[4][4] = {};

  const int nsteps = g.K >> 5;
  float4 v[4];
  stage_load<AMODE>(g, row0, 0, v);
  stage_write(Ah[0], Al[0], v);
  __syncthreads();

  for (int s = 0; s < nsteps; s++){
    const int cur = s & 1, nxt = cur ^ 1;
    const bool have = (s + 1) < nsteps;
    if (have) stage_load<AMODE>(g, row0, (s + 1) << 5, v);

    // B fragments for this k-step (global, L2-hot, identical across blocks)
    bf16x8 bh[4], bl[4];
    const size_t bbase = ((size_t)s * 8 + ch * 4) * 64 * 8 + (size_t)lane * 8;
    #pragma unroll
    for (int nf = 0; nf < 4; nf++){
      bh[nf] = *(const bf16x8*)(g.Bph + bbase + (size_t)nf * 64 * 8);
      bl[nf] = *(const bf16x8*)(g.Bpl + bbase + (size_t)nf * 64 * 8);
    }
    #pragma unroll
    for (int mf = 0; mf < 4; mf++){
      const int ao = (rh*64 + mf*16 + lrow) * ASTR + lk * 8;
      bf16x8 ah  = *(const bf16x8*)&Ah[cur][ao];
      bf16x8 alo = *(const bf16x8*)&Al[cur][ao];
      #pragma unroll
      for (int nf = 0; nf < 4; nf++){
        acc[mf][nf] = __builtin_amdgcn_mfma_f32_16x16x32_bf16(ah,  bh[nf], acc[mf][nf], 0, 0, 0);
        acc[mf][nf] = __builtin_amdgcn_mfma_f32_16x16x32_bf16(ah,  bl[nf], acc[mf][nf], 0, 0, 0);
        acc[mf][nf] = __builtin_amdgcn_mfma_f32_16x16x32_bf16(alo, bh[nf], acc[mf][nf], 0, 0, 0);
      }
    }
    if (have) stage_write(Ah[nxt], Al[nxt], v);
    __syncthreads();
  }

  #pragma unroll
  for (int mf = 0; mf < 4; mf++){
    #pragma unroll
    for (int nf = 0; nf < 4; nf++){
      const int col = ch*64 + nf*16 + lrow;
      const float b = g.bias[col];
      #pragma unroll
      for (int j = 0; j < 4; j++){
        const int r = row0 + rh*64 + mf*16 + lk*4 + j;
        if (r < g.M){
          float val = acc[mf][nf][j] + b;
          if constexpr (EPI == 1) val = fmaxf(val, 0.f);
          float* cp = g.C + (size_t)r * HDIM + col;
          if constexpr (EPI == 2) val = *cp + 0.5f * val;
          *cp = val;
        }
      }
    }
  }
}

// ===========================================================================
// B-prep: fp32 W[K,128] -> fragment-ordered bf16 hi/lo arrays.
// Layout: Bp[(kq*8+n)*64 + lane][i] , element = W[kq*32+(lane>>4)*8+i][n*16+(lane&15)]
// ===========================================================================
__global__ void bprep_k(const float* __restrict__ W, unsigned short* __restrict__ Bph,
                        unsigned short* __restrict__ Bpl){
  const int bb = blockIdx.x;           // kq*8 + n
  const int kq = bb >> 3, n = bb & 7;
  const int l = threadIdx.x;           // 64
  const int colg = n*16 + (l & 15);
  const int krow = kq*32 + (l >> 4)*8;
  float vv[8];
  #pragma unroll
  for (int i = 0; i < 8; i++) vv[i] = W[(size_t)(krow + i) * HDIM + colg];
  ushort4 h0, h1, l0, l1;
  h0.x=f2bf(vv[0]); l0.x=f2bf(vv[0]-bf2f(h0.x));
  h0.y=f2bf(vv[1]); l0.y=f2bf(vv[1]-bf2f(h0.y));
  h0.z=f2bf(vv[2]); l0.z=f2bf(vv[2]-bf2f(h0.z));
  h0.w=f2bf(vv[3]); l0.w=f2bf(vv[3]-bf2f(h0.w));
  h1.x=f2bf(vv[4]); l1.x=f2bf(vv[4]-bf2f(h1.x));
  h1.y=f2bf(vv[5]); l1.y=f2bf(vv[5]-bf2f(h1.y));
  h1.z=f2bf(vv[6]); l1.z=f2bf(vv[6]-bf2f(h1.z));
  h1.w=f2bf(vv[7]); l1.w=f2bf(vv[7]-bf2f(h1.w));
  const size_t o = ((size_t)bb * 64 + l) * 8;
  *(ushort4*)&Bph[o]   = h0; *(ushort4*)&Bph[o+4] = h1;
  *(ushort4*)&Bpl[o]   = l0; *(ushort4*)&Bpl[o+4] = l1;
}

// ===========================================================================
// Small fp32 tiled GEMM for weight combining (M<=1664, K=128, N=128).
// ===========================================================================
template<int AMODE_UNUSED, int EPI_UNUSED>
__global__ __launch_bounds__(256) void gemm_k(GArgs g){
  __shared__ float As[16][68];
  __shared__ float Bs[16][68];
  const int tid = threadIdx.x;
  const int tx = tid & 15, ty = tid >> 4;
  const int row0 = blockIdx.y * 64, col0 = blockIdx.x * 64;
  float acc[4][4] = {};
  for (int k0 = 0; k0 < g.K; k0 += 16){
    #pragma unroll
    for (int i = 0; i < 4; i++){
      int l = tid + i * 256;
      int ar = l >> 4, ak = l & 15;
      int gr = row0 + ar;
      float v = 0.f;
      if (gr < g.M) v = g.A[(size_t)gr * g.K + k0 + ak];
      As[ak][ar] = v;
    }
    #pragma unroll
    for (int i = 0; i < 4; i++){
      int l = tid + i * 256;
      int bn_ = l & 63, bk = l >> 6;
      Bs[bk][bn_] = g.B[(size_t)(k0 + bk) * HDIM + col0 + bn_];
    }
    __syncthreads();
    #pragma unroll
    for (int kk = 0; kk < 16; kk++){
      float a[4], b[4];
      #pragma unroll
      for (int j = 0; j < 4; j++) a[j] = As[kk][ty*4 + j];
      #pragma unroll
      for (int j = 0; j < 4; j++) b[j] = Bs[kk][tx*4 + j];
      #pragma unroll
      for (int ii = 0; ii < 4; ii++)
        #pragma unroll
        for (int jj = 0; jj < 4; jj++)
          acc[ii][jj] = fmaf(a[ii], b[jj], acc[ii][jj]);
    }
    __syncthreads();
  }
  #pragma unroll
  for (int ii = 0; ii < 4; ii++){
    int gr = row0 + ty*4 + ii;
    if (gr >= g.M) continue;
    #pragma unroll
    for (int jj = 0; jj < 4; jj++)
      g.C[(size_t)gr * HDIM + col0 + tx*4 + jj] = acc[ii][jj];
  }
}

// ---------------- scatter / aggregation ----------------
__device__ __forceinline__ unsigned fmap(float x){
  unsigned u = __float_as_uint(x);
  return (u & 0x80000000u) ? ~u : (u | 0x80000000u);
}
__device__ __forceinline__ float funmap(unsigned m){
  unsigned u = (m & 0x80000000u) ? (m & 0x7FFFFFFFu) : ~m;
  return __uint_as_float(u);
}

__global__ void init_agg_k(float* sum, float* sumsq, unsigned* minb, unsigned* maxb){
  int i = blockIdx.x * 256 + threadIdx.x;
  if (i < NODES * HDIM){
    sum[i] = 0.f; sumsq[i] = 0.f;
    minb[i] = 0xFFFFFFFFu; maxb[i] = 0u;
  }
}

__global__ void scatter_k(const float* __restrict__ h, const int* __restrict__ dst,
                          float* sum, float* sumsq, unsigned* minb, unsigned* maxb){
  int i = blockIdx.x * 256 + threadIdx.x;
  if (i >= EDGES * HDIM) return;
  int e = i >> 7, c = i & 127;
  int d = dst[e];
  float v = h[i];
  int o = d * HDIM + c;
  atomicAdd(&sum[o], v);
  atomicAdd(&sumsq[o], v * v);
  unsigned m = fmap(v);
  atomicMax(&maxb[o], m);
  atomicMin(&minb[o], m);
}

__global__ void finalize_k(const float* __restrict__ sum, const float* __restrict__ sumsq,
                           const unsigned* __restrict__ minb, const unsigned* __restrict__ maxb,
                           const int* __restrict__ cnt, float* __restrict__ agg){
  int i = blockIdx.x * 256 + threadIdx.x;
  if (i >= NODES * HDIM) return;
  int n = i >> 7, c = i & 127;
  float cn = (float)cnt[n];
  float degc = fmaxf(cn, 1.f);
  float mean = sum[i] / degc;
  float msq  = sumsq[i] / degc;
  float var  = fmaxf(msq - mean * mean, 0.f);
  float sd   = sqrtf(var + EPS_STD);
  float mn = (cn > 0.f) ? funmap(minb[i]) : 0.f;
  float mx = (cn > 0.f) ? funmap(maxb[i]) : 0.f;
  float* a = agg + (size_t)n * 512;
  a[c]       = mean;
  a[128 + c] = mn;
  a[256 + c] = mx;
  a[384 + c] = sd;
}

// ---------------- degree (computed once; dst constant across layers) -------
__global__ void deg_init_k(int* cnt){
  int i = blockIdx.x * 256 + threadIdx.x;
  if (i < NODES) cnt[i] = 0;
}
__global__ void deg_count_k(const int* __restrict__ dst, int* cnt){
  int e = blockIdx.x * 256 + threadIdx.x;
  if (e < EDGES) atomicAdd(&cnt[dst[e]], 1);
}
__global__ void deg_fin_k(const int* __restrict__ cnt, float* fdeg, float* invf){
  int i = blockIdx.x * 256 + threadIdx.x;
  if (i < NODES){
    float d = fmaxf((float)cnt[i], 1.f);
    float f = logf(d + 1.f) / AVG_DEG_LOG;
    fdeg[i] = f;
    invf[i] = 1.f / f;
  }
}

// ---------------- BN + residual ----------------
__global__ __launch_bounds__(256) void bn_stats_k(const float* __restrict__ out2, float* mu, float* var){
  __shared__ float sh1[256], sh2[256];
  int c = blockIdx.x;
  float s = 0.f, ss = 0.f;
  for (int r = threadIdx.x; r < NODES; r += 256){
    float v = out2[(size_t)r * HDIM + c];
    s += v; ss += v * v;
  }
  sh1[threadIdx.x] = s; sh2[threadIdx.x] = ss;
  __syncthreads();
  for (int o = 128; o > 0; o >>= 1){
    if (threadIdx.x < o){ sh1[threadIdx.x] += sh1[threadIdx.x + o]; sh2[threadIdx.x] += sh2[threadIdx.x + o]; }
    __syncthreads();
  }
  if (threadIdx.x == 0){
    float m = sh1[0] / (float)NODES;
    mu[c] = m;
    var[c] = sh2[0] / (float)NODES - m * m;
  }
}

__global__ void xh_update_k(float* __restrict__ xh, const float* __restrict__ out2,
                            const float* __restrict__ mu, const float* __restrict__ var,
                            const float* __restrict__ gamma, const float* __restrict__ beta){
  int i = blockIdx.x * 256 + threadIdx.x;
  if (i >= NODES * HDIM) return;
  int c = i & 127;
  float bn = gamma[c] * (out2[i] - mu[c]) * rsqrtf(var[c] + EPS_BN) + beta[c];
  xh[i] = (xh[i] + fmaxf(bn, 0.f)) * 0.5f;
}

// ---------------- misc small kernels ----------------
__global__ void zero_k(float* p, int n){
  int i = blockIdx.x * 256 + threadIdx.x;
  if (i < n) p[i] = 0.f;
}
__global__ void copy_k(float* __restrict__ d, const float* __restrict__ s, int n){
  int i = blockIdx.x * 256 + threadIdx.x;
  if (i < n) d[i] = s[i];
}
// bout[j] = badd[j] + sum_k bin[k] * W[k*128 + j]
__global__ void bias_comb_k(const float* __restrict__ bin, const float* __restrict__ W,
                            const float* __restrict__ badd, float* __restrict__ bout){
  int j = threadIdx.x;
  float s = badd[j];
  for (int k = 0; k < HDIM; k++) s = fmaf(bin[k], W[(size_t)k * HDIM + j], s);
  bout[j] = s;
}

// ===========================================================================
extern "C" void kernel_launch(void* const* d_in, const int* in_sizes, int n_in,
                              void* d_out, int out_size, void* d_ws, size_t ws_size,
                              hipStream_t stream) {
  const float* x      = (const float*)d_in[0];
  const int*   ei     = (const int*)  d_in[1];
  const float* ea     = (const float*)d_in[2];
  const float* W_node = (const float*)d_in[3];
  const float* b_node = (const float*)d_in[4];
  const float* W_edge = (const float*)d_in[5];
  const float* b_edge = (const float*)d_in[6];
  const float* W_ee   = (const float*)d_in[7];
  const float* b_ee   = (const float*)d_in[8];
  const float* W_pre  = (const float*)d_in[9];
  const float* b_pre  = (const float*)d_in[10];
  const float* W_post = (const float*)d_in[11];
  const float* b_post = (const float*)d_in[12];
  const float* W_lin  = (const float*)d_in[13];
  const float* b_lin  = (const float*)d_in[14];
  const float* gamma  = (const float*)d_in[15];
  const float* beta   = (const float*)d_in[16];
  const float* We1    = (const float*)d_in[17];
  const float* be1    = (const float*)d_in[18];
  const float* We2    = (const float*)d_in[19];
  const float* be2    = (const float*)d_in[20];

  const int* src = ei;
  const int* dst = ei + EDGES;

  float* xh = (float*)d_out;
  float* e  = xh + (size_t)NODES * HDIM;

  // ---- workspace bump allocator (64B aligned regions) ----
  char* wp = (char*)d_ws;
  auto alloc = [&](size_t bytes) -> char* {
    char* r = wp;
    wp += (bytes + 63) & ~(size_t)63;
    return r;
  };
  float* h     = (float*)alloc((size_t)EDGES * HDIM * 4);
  float* agg   = (float*)alloc((size_t)NODES * 512 * 4);
  float* sum   = (float*)alloc((size_t)NODES * HDIM * 4);
  float* sumsq = (float*)alloc((size_t)NODES * HDIM * 4);
  float* out2  = (float*)alloc((size_t)NODES * HDIM * 4);
  unsigned* minb = (unsigned*)alloc((size_t)NODES * HDIM * 4);
  unsigned* maxb = (unsigned*)alloc((size_t)NODES * HDIM * 4);
  int*   cnt  = (int*)  alloc(NODES * 4);
  float* fdeg = (float*)alloc(NODES * 4);
  float* invf = (float*)alloc(NODES * 4);
  float* Wc1  = (float*)alloc(384 * HDIM * 4);     // [Wp1;Wp2;W_ee@Wp3]
  float* Wc2  = (float*)alloc(1664 * HDIM * 4);    // W_post@W_lin
  float* bc1  = (float*)alloc(HDIM * 4);
  float* bc2  = (float*)alloc(HDIM * 4);
  float* zb   = (float*)alloc(HDIM * 4);
  float* mu   = (float*)alloc(HDIM * 4);
  float* var  = (float*)alloc(HDIM * 4);
  auto allocS = [&](int K) -> unsigned short* { return (unsigned short*)alloc((size_t)K * HDIM * 2); };
  unsigned short* BpNh = allocS(64);   unsigned short* BpNl = allocS(64);
  unsigned short* BpEh = allocS(32);   unsigned short* BpEl = allocS(32);
  unsigned short* Bp1h = allocS(384);  unsigned short* Bp1l = allocS(384);
  unsigned short* Bp2h = allocS(1664); unsigned short* Bp2l = allocS(1664);
  unsigned short* Bp3h = allocS(384);  unsigned short* Bp3l = allocS(384);
  unsigned short* Bp4h = allocS(128);  unsigned short* Bp4l = allocS(128);

  dim3 blk(256);
  auto mgrid = [](int M){ return dim3(1, (M + 127) / 128); };
  auto bgrid = [](int K){ return dim3((K / 32) * 8); };

  GArgs g{};

  // ---- once-per-call prep ----
  zero_k<<<1, 128, 0, stream>>>(zb, HDIM);
  deg_init_k <<<(NODES + 255) / 256, blk, 0, stream>>>(cnt);
  deg_count_k<<<(EDGES + 255) / 256, blk, 0, stream>>>(dst, cnt);
  deg_fin_k  <<<(NODES + 255) / 256, blk, 0, stream>>>(cnt, fdeg, invf);

  bprep_k<<<bgrid(FDIM), 64, 0, stream>>>(W_node, BpNh, BpNl);
  bprep_k<<<bgrid(DDIM), 64, 0, stream>>>(W_edge, BpEh, BpEl);

  // xh = x @ W_node + b_node
  g = GArgs{}; g.A = x; g.Bph = BpNh; g.Bpl = BpNl; g.bias = b_node; g.C = xh;
  g.M = NODES; g.K = FDIM;
  mgemm_k<0,0><<<mgrid(NODES), blk, 0, stream>>>(g);

  // e = edge_attr @ W_edge + b_edge
  g = GArgs{}; g.A = ea; g.Bph = BpEh; g.Bpl = BpEl; g.bias = b_edge; g.C = e;
  g.M = EDGES; g.K = DDIM;
  mgemm_k<0,0><<<mgrid(EDGES), blk, 0, stream>>>(g);

  for (int l = 0; l < 2; l++){
    const float* W_ee_l   = W_ee   + (size_t)l * HDIM * HDIM;
    const float* b_ee_l   = b_ee   + l * HDIM;
    const float* W_pre_l  = W_pre  + (size_t)l * 3 * HDIM * HDIM;
    const float* b_pre_l  = b_pre  + l * HDIM;
    const float* W_post_l = W_post + (size_t)l * 13 * HDIM * HDIM;
    const float* b_post_l = b_post + l * HDIM;
    const float* W_lin_l  = W_lin  + (size_t)l * HDIM * HDIM;
    const float* b_lin_l  = b_lin  + l * HDIM;
    const float* gamma_l  = gamma  + l * HDIM;
    const float* beta_l   = beta   + l * HDIM;
    const float* We1_l    = We1    + (size_t)l * 3 * HDIM * HDIM;
    const float* be1_l    = be1    + l * HDIM;
    const float* We2_l    = We2    + (size_t)l * HDIM * HDIM;
    const float* be2_l    = be2    + l * HDIM;
    const float* Wp3      = W_pre_l + (size_t)2 * HDIM * HDIM;  // rows 256..383

    // Wc1 = [Wp1;Wp2 ; W_ee @ Wp3],  bc1 = b_pre + b_ee@Wp3
    copy_k<<<(2 * HDIM * HDIM + 255) / 256, blk, 0, stream>>>(Wc1, W_pre_l, 2 * HDIM * HDIM);
    g = GArgs{}; g.A = W_ee_l; g.B = Wp3; g.C = Wc1 + (size_t)2 * HDIM * HDIM;
    g.M = HDIM; g.K = HDIM;
    gemm_k<0,0><<<dim3(2, 2), blk, 0, stream>>>(g);
    bias_comb_k<<<1, HDIM, 0, stream>>>(b_ee_l, Wp3, b_pre_l, bc1);
    bprep_k<<<bgrid(3 * HDIM), 64, 0, stream>>>(Wc1, Bp1h, Bp1l);

    // h = [xh[dst], xh[src], e] @ Wc1 + bc1
    g = GArgs{}; g.A = e; g.s0 = xh; g.s1 = xh; g.i0 = dst; g.i1 = src;
    g.Bph = Bp1h; g.Bpl = Bp1l; g.bias = bc1; g.C = h; g.M = EDGES; g.K = 3 * HDIM;
    mgemm_k<1,0><<<mgrid(EDGES), blk, 0, stream>>>(g);

    // multi-aggregator scatter at dst
    init_agg_k<<<(NODES * HDIM + 255) / 256, blk, 0, stream>>>(sum, sumsq, minb, maxb);
    scatter_k<<<(EDGES * HDIM + 255) / 256, blk, 0, stream>>>(h, dst, sum, sumsq, minb, maxb);
    finalize_k<<<(NODES * HDIM + 255) / 256, blk, 0, stream>>>(sum, sumsq, minb, maxb, cnt, agg);

    // Wc2 = W_post @ W_lin, bc2 = b_lin + b_post@W_lin
    g = GArgs{}; g.A = W_post_l; g.B = W_lin_l; g.C = Wc2; g.M = 13 * HDIM; g.K = HDIM;
    gemm_k<0,0><<<dim3(2, 26), blk, 0, stream>>>(g);
    bias_comb_k<<<1, HDIM, 0, stream>>>(b_post_l, W_lin_l, b_lin_l, bc2);
    bprep_k<<<bgrid(13 * HDIM), 64, 0, stream>>>(Wc2, Bp2h, Bp2l);

    // out2 = [xh, agg, agg*f, agg/f] @ Wc2 + bc2
    g = GArgs{}; g.A = xh; g.agg = agg; g.fs = fdeg; g.invfs = invf;
    g.Bph = Bp2h; g.Bpl = Bp2l; g.bias = bc2; g.C = out2; g.M = NODES; g.K = 13 * HDIM;
    mgemm_k<2,0><<<mgrid(NODES), blk, 0, stream>>>(g);

    // BN + residual relu
    bn_stats_k<<<HDIM, blk, 0, stream>>>(out2, mu, var);
    xh_update_k<<<(NODES * HDIM + 255) / 256, blk, 0, stream>>>(xh, out2, mu, var, gamma_l, beta_l);

    // t1 = relu([xh[src], xh[dst], e] @ We1 + be1)   (t1 reuses h)
    bprep_k<<<bgrid(3 * HDIM), 64, 0, stream>>>(We1_l, Bp3h, Bp3l);
    g = GArgs{}; g.A = e; g.s0 = xh; g.s1 = xh; g.i0 = src; g.i1 = dst;
    g.Bph = Bp3h; g.Bpl = Bp3l; g.bias = be1_l; g.C = h; g.M = EDGES; g.K = 3 * HDIM;
    mgemm_k<1,1><<<mgrid(EDGES), blk, 0, stream>>>(g);

    // e += 0.5 * (t1 @ We2 + be2)
    bprep_k<<<bgrid(HDIM), 64, 0, stream>>>(We2_l, Bp4h, Bp4l);
    g = GArgs{}; g.A = h; g.Bph = Bp4h; g.Bpl = Bp4l; g.bias = be2_l; g.C = e;
    g.M = EDGES; g.K = HDIM;
    mgemm_k<0,2><<<mgrid(EDGES), blk, 0, stream>>>(g);
  }
}

// Round 3
// 1026.646 us; speedup vs baseline: 2.7767x; 1.3519x over previous
//
#include <hip/hip_runtime.h>

// PNA GNN (2 layers) on MI355X — bf16x3 MFMA GEMMs + fused gathers + CSR aggregation.
#define NODES 10000
#define EDGES 160000
#define FDIM 64
#define DDIM 32
#define HDIM 128
#define AVG_DEG_LOG 2.8332133440562162f   // log(17)
#define EPS_BN 1e-5f
#define EPS_STD 1e-5f

typedef short bf16x8 __attribute__((ext_vector_type(8)));   // 8 bf16 (4 VGPRs)
typedef float f32x4  __attribute__((ext_vector_type(4)));   // 4 fp32

struct GArgs {
  const float* A;
  const float* s0;
  const float* s1;
  const int*   i0;
  const int*   i1;
  const float* agg;
  const float* fs;
  const float* invfs;
  const float* B;       // fp32 B for the small weight-combine GEMM
  const unsigned short* Bph;  // prepped bf16-hi fragments
  const unsigned short* Bpl;  // prepped bf16-lo fragments
  const float* bias;
  float*       C;
  int M, K;
};

// ---------------- bf16 helpers ----------------
__device__ __forceinline__ unsigned short f2bf(float x){
  unsigned u = __float_as_uint(x);
  return (unsigned short)((u + 0x7FFFu + ((u >> 16) & 1u)) >> 16);
}
__device__ __forceinline__ float bf2f(unsigned short h){
  return __uint_as_float(((unsigned)h) << 16);
}

// ===========================================================================
// MFMA GEMM: C[M,128] = gatherA[M,K] @ W[K,128] + bias, bf16x3 split.
// Block: 256 thr (4 waves), BM=128, BN=128, BK=32, double-buffered LDS.
// AMODE 0: direct [M,K]; 1: [s0[i0], s1[i1], A]; 2: [A | agg | agg*fs | agg*invfs]
// EPI 0: store; 1: relu-store; 2: C += 0.5*(acc+bias).
// ===========================================================================
#define BK 32
#define APAD 8
#define ASTR (BK + APAD)   // 40 bf16 = 80 B row stride (2-way bank alias: free)

template<int AMODE>
__device__ __forceinline__ void stage_load(const GArgs& g, int row0, int k0, float4 (&v)[4]){
  const int tid = threadIdx.x;
  const int r  = tid >> 1;
  const int c0 = (tid & 1) << 4;      // 0 or 16 floats within the 32-wide tile
  const int gr = row0 + r;
  if (gr >= g.M){
    v[0] = v[1] = v[2] = v[3] = make_float4(0.f, 0.f, 0.f, 0.f);
    return;
  }
  const int kk = k0 + c0;
  const float* p;
  float scale = 1.f;
  if constexpr (AMODE == 0){
    p = g.A + (size_t)gr * g.K + kk;
  } else if constexpr (AMODE == 1){
    if (kk < HDIM)          p = g.s0 + (size_t)g.i0[gr] * HDIM + kk;
    else if (kk < 2*HDIM)   p = g.s1 + (size_t)g.i1[gr] * HDIM + (kk - HDIM);
    else                    p = g.A  + (size_t)gr * HDIM + (kk - 2*HDIM);
  } else {
    if (kk < HDIM){
      p = g.A + (size_t)gr * HDIM + kk;
    } else {
      int q = kk - HDIM; int seg = q >> 9;
      p = g.agg + (size_t)gr * 512 + (q & 511);
      if (seg == 1)      scale = g.fs[gr];
      else if (seg == 2) scale = g.invfs[gr];
    }
  }
  const float4* p4 = (const float4*)p;
  v[0] = p4[0]; v[1] = p4[1]; v[2] = p4[2]; v[3] = p4[3];
  if (scale != 1.f){
    #pragma unroll
    for (int j = 0; j < 4; j++){
      v[j].x *= scale; v[j].y *= scale; v[j].z *= scale; v[j].w *= scale;
    }
  }
}

__device__ __forceinline__ void stage_write(unsigned short* __restrict__ AhB,
                                            unsigned short* __restrict__ AlB,
                                            const float4 (&v)[4]){
  const int tid = threadIdx.x;
  const int base = (tid >> 1) * ASTR + ((tid & 1) << 4);
  #pragma unroll
  for (int j = 0; j < 4; j++){
    ushort4 h, l;
    h.x = f2bf(v[j].x); l.x = f2bf(v[j].x - bf2f(h.x));
    h.y = f2bf(v[j].y); l.y = f2bf(v[j].y - bf2f(h.y));
    h.z = f2bf(v[j].z); l.z = f2bf(v[j].z - bf2f(h.z));
    h.w = f2bf(v[j].w); l.w = f2bf(v[j].w - bf2f(h.w));
    *(ushort4*)&AhB[base + j*4] = h;
    *(ushort4*)&AlB[base + j*4] = l;
  }
}

template<int AMODE, int EPI>
__global__ __launch_bounds__(256) void mgemm_k(GArgs g){
  __shared__ unsigned short Ah[2][128 * ASTR];
  __shared__ unsigned short Al[2][128 * ASTR];
  const int tid  = threadIdx.x;
  const int row0 = blockIdx.y * 128;
  const int wave = tid >> 6, lane = tid & 63;
  const int rh = wave >> 1, ch = wave & 1;
  const int lrow = lane & 15, lk = lane >> 4;

  f32x4 acc[4][4] = {};

  const int nsteps = g.K >> 5;
  float4 v[4];
  stage_load<AMODE>(g, row0, 0, v);
  stage_write(Ah[0], Al[0], v);
  __syncthreads();

  for (int s = 0; s < nsteps; s++){
    const int cur = s & 1, nxt = cur ^ 1;
    const bool have = (s + 1) < nsteps;
    if (have) stage_load<AMODE>(g, row0, (s + 1) << 5, v);

    bf16x8 bh[4], bl[4];
    const size_t bbase = ((size_t)s * 8 + ch * 4) * 64 * 8 + (size_t)lane * 8;
    #pragma unroll
    for (int nf = 0; nf < 4; nf++){
      bh[nf] = *(const bf16x8*)(g.Bph + bbase + (size_t)nf * 64 * 8);
      bl[nf] = *(const bf16x8*)(g.Bpl + bbase + (size_t)nf * 64 * 8);
    }
    #pragma unroll
    for (int mf = 0; mf < 4; mf++){
      const int ao = (rh*64 + mf*16 + lrow) * ASTR + lk * 8;
      bf16x8 ah  = *(const bf16x8*)&Ah[cur][ao];
      bf16x8 alo = *(const bf16x8*)&Al[cur][ao];
      #pragma unroll
      for (int nf = 0; nf < 4; nf++){
        acc[mf][nf] = __builtin_amdgcn_mfma_f32_16x16x32_bf16(ah,  bh[nf], acc[mf][nf], 0, 0, 0);
        acc[mf][nf] = __builtin_amdgcn_mfma_f32_16x16x32_bf16(ah,  bl[nf], acc[mf][nf], 0, 0, 0);
        acc[mf][nf] = __builtin_amdgcn_mfma_f32_16x16x32_bf16(alo, bh[nf], acc[mf][nf], 0, 0, 0);
      }
    }
    if (have) stage_write(Ah[nxt], Al[nxt], v);
    __syncthreads();
  }

  #pragma unroll
  for (int mf = 0; mf < 4; mf++){
    #pragma unroll
    for (int nf = 0; nf < 4; nf++){
      const int col = ch*64 + nf*16 + lrow;
      const float b = g.bias[col];
      #pragma unroll
      for (int j = 0; j < 4; j++){
        const int r = row0 + rh*64 + mf*16 + lk*4 + j;
        if (r < g.M){
          float val = acc[mf][nf][j] + b;
          if constexpr (EPI == 1) val = fmaxf(val, 0.f);
          float* cp = g.C + (size_t)r * HDIM + col;
          if constexpr (EPI == 2) val = *cp + 0.5f * val;
          *cp = val;
        }
      }
    }
  }
}

// ===========================================================================
// B-prep: fp32 W[K,128] -> fragment-ordered bf16 hi/lo arrays.
// ===========================================================================
__global__ void bprep_k(const float* __restrict__ W, unsigned short* __restrict__ Bph,
                        unsigned short* __restrict__ Bpl){
  const int bb = blockIdx.x;           // kq*8 + n
  const int kq = bb >> 3, n = bb & 7;
  const int l = threadIdx.x;           // 64
  const int colg = n*16 + (l & 15);
  const int krow = kq*32 + (l >> 4)*8;
  float vv[8];
  #pragma unroll
  for (int i = 0; i < 8; i++) vv[i] = W[(size_t)(krow + i) * HDIM + colg];
  ushort4 h0, h1, l0, l1;
  h0.x=f2bf(vv[0]); l0.x=f2bf(vv[0]-bf2f(h0.x));
  h0.y=f2bf(vv[1]); l0.y=f2bf(vv[1]-bf2f(h0.y));
  h0.z=f2bf(vv[2]); l0.z=f2bf(vv[2]-bf2f(h0.z));
  h0.w=f2bf(vv[3]); l0.w=f2bf(vv[3]-bf2f(h0.w));
  h1.x=f2bf(vv[4]); l1.x=f2bf(vv[4]-bf2f(h1.x));
  h1.y=f2bf(vv[5]); l1.y=f2bf(vv[5]-bf2f(h1.y));
  h1.z=f2bf(vv[6]); l1.z=f2bf(vv[6]-bf2f(h1.z));
  h1.w=f2bf(vv[7]); l1.w=f2bf(vv[7]-bf2f(h1.w));
  const size_t o = ((size_t)bb * 64 + l) * 8;
  *(ushort4*)&Bph[o]   = h0; *(ushort4*)&Bph[o+4] = h1;
  *(ushort4*)&Bpl[o]   = l0; *(ushort4*)&Bpl[o+4] = l1;
}

// ===========================================================================
// Small fp32 tiled GEMM for weight combining (M<=1664, K=128, N=128).
// ===========================================================================
template<int AMODE_UNUSED, int EPI_UNUSED>
__global__ __launch_bounds__(256) void gemm_k(GArgs g){
  __shared__ float As[16][68];
  __shared__ float Bs[16][68];
  const int tid = threadIdx.x;
  const int tx = tid & 15, ty = tid >> 4;
  const int row0 = blockIdx.y * 64, col0 = blockIdx.x * 64;
  float acc[4][4] = {};
  for (int k0 = 0; k0 < g.K; k0 += 16){
    #pragma unroll
    for (int i = 0; i < 4; i++){
      int l = tid + i * 256;
      int ar = l >> 4, ak = l & 15;
      int gr = row0 + ar;
      float v = 0.f;
      if (gr < g.M) v = g.A[(size_t)gr * g.K + k0 + ak];
      As[ak][ar] = v;
    }
    #pragma unroll
    for (int i = 0; i < 4; i++){
      int l = tid + i * 256;
      int bn_ = l & 63, bk = l >> 6;
      Bs[bk][bn_] = g.B[(size_t)(k0 + bk) * HDIM + col0 + bn_];
    }
    __syncthreads();
    #pragma unroll
    for (int kk = 0; kk < 16; kk++){
      float a[4], b[4];
      #pragma unroll
      for (int j = 0; j < 4; j++) a[j] = As[kk][ty*4 + j];
      #pragma unroll
      for (int j = 0; j < 4; j++) b[j] = Bs[kk][tx*4 + j];
      #pragma unroll
      for (int ii = 0; ii < 4; ii++)
        #pragma unroll
        for (int jj = 0; jj < 4; jj++)
          acc[ii][jj] = fmaf(a[ii], b[jj], acc[ii][jj]);
    }
    __syncthreads();
  }
  #pragma unroll
  for (int ii = 0; ii < 4; ii++){
    int gr = row0 + ty*4 + ii;
    if (gr >= g.M) continue;
    #pragma unroll
    for (int jj = 0; jj < 4; jj++)
      g.C[(size_t)gr * HDIM + col0 + tx*4 + jj] = acc[ii][jj];
  }
}

// ===========================================================================
// CSR build over dst (constant across layers): deg count -> scan -> fill.
// ===========================================================================
__global__ void deg_init_k(int* cnt, int* cursor){
  int i = blockIdx.x * 256 + threadIdx.x;
  if (i < NODES){ cnt[i] = 0; cursor[i] = 0; }
}
__global__ void deg_count_k(const int* __restrict__ dst, int* cnt){
  int e = blockIdx.x * 256 + threadIdx.x;
  if (e < EDGES) atomicAdd(&cnt[dst[e]], 1);
}
__global__ void deg_fin_k(const int* __restrict__ cnt, float* fdeg, float* invf){
  int i = blockIdx.x * 256 + threadIdx.x;
  if (i < NODES){
    float d = fmaxf((float)cnt[i], 1.f);
    float f = logf(d + 1.f) / AVG_DEG_LOG;
    fdeg[i] = f;
    invf[i] = 1.f / f;
  }
}
// Single-block exclusive scan of cnt[NODES] -> off[NODES] (+ off[NODES]=E).
__global__ __launch_bounds__(256) void scan_k(const int* __restrict__ cnt, int* __restrict__ off){
  __shared__ int sh[256];
  __shared__ int carry;
  if (threadIdx.x == 0) carry = 0;
  __syncthreads();
  for (int base = 0; base < NODES; base += 256){
    int i = base + threadIdx.x;
    int v = (i < NODES) ? cnt[i] : 0;
    sh[threadIdx.x] = v;
    __syncthreads();
    #pragma unroll
    for (int o = 1; o < 256; o <<= 1){
      int t = (threadIdx.x >= o) ? sh[threadIdx.x - o] : 0;
      __syncthreads();
      sh[threadIdx.x] += t;
      __syncthreads();
    }
    if (i < NODES) off[i] = carry + sh[threadIdx.x] - v;   // exclusive
    __syncthreads();
    if (threadIdx.x == 255) carry += sh[255];
    __syncthreads();
  }
  if (threadIdx.x == 0) off[NODES] = carry;
}
__global__ void csr_fill_k(const int* __restrict__ dst, const int* __restrict__ off,
                           int* cursor, int* __restrict__ eidx){
  int e = blockIdx.x * 256 + threadIdx.x;
  if (e < EDGES){
    int d = dst[e];
    int p = atomicAdd(&cursor[d], 1);
    eidx[off[d] + p] = e;
  }
}

// ===========================================================================
// CSR aggregation: block = 256 thr = 2 nodes x 128 cols. Fuses finalize.
// agg[node][0:512] = [mean | min | max | std]
// ===========================================================================
__global__ __launch_bounds__(256) void aggregate_k(const float* __restrict__ h,
                                                   const int* __restrict__ off,
                                                   const int* __restrict__ eidx,
                                                   float* __restrict__ agg){
  const int node = blockIdx.x * 2 + (threadIdx.x >> 7);
  const int c = threadIdx.x & 127;
  if (node >= NODES) return;
  const int o0 = off[node], o1 = off[node + 1];
  const int d  = o1 - o0;
  float s = 0.f, ss = 0.f, mn = INFINITY, mx = -INFINITY;
  for (int k = o0; k < o1; k++){
    float vv = h[(size_t)eidx[k] * HDIM + c];
    s += vv; ss += vv * vv;
    mn = fminf(mn, vv); mx = fmaxf(mx, vv);
  }
  const float degc = fmaxf((float)d, 1.f);
  const float mean = s / degc;
  const float msq  = ss / degc;
  const float sd   = sqrtf(fmaxf(msq - mean * mean, 0.f) + EPS_STD);
  if (d == 0){ mn = 0.f; mx = 0.f; }
  float* a = agg + (size_t)node * 512;
  a[c]       = mean;
  a[128 + c] = mn;
  a[256 + c] = mx;
  a[384 + c] = sd;
}

// ---------------- BN + residual ----------------
__global__ __launch_bounds__(256) void bn_stats_k(const float* __restrict__ out2, float* mu, float* var){
  __shared__ float sh1[256], sh2[256];
  int c = blockIdx.x;
  float s = 0.f, ss = 0.f;
  for (int r = threadIdx.x; r < NODES; r += 256){
    float v = out2[(size_t)r * HDIM + c];
    s += v; ss += v * v;
  }
  sh1[threadIdx.x] = s; sh2[threadIdx.x] = ss;
  __syncthreads();
  for (int o = 128; o > 0; o >>= 1){
    if (threadIdx.x < o){ sh1[threadIdx.x] += sh1[threadIdx.x + o]; sh2[threadIdx.x] += sh2[threadIdx.x + o]; }
    __syncthreads();
  }
  if (threadIdx.x == 0){
    float m = sh1[0] / (float)NODES;
    mu[c] = m;
    var[c] = sh2[0] / (float)NODES - m * m;
  }
}

__global__ void xh_update_k(float* __restrict__ xh, const float* __restrict__ out2,
                            const float* __restrict__ mu, const float* __restrict__ var,
                            const float* __restrict__ gamma, const float* __restrict__ beta){
  int i = blockIdx.x * 256 + threadIdx.x;
  if (i >= NODES * HDIM) return;
  int c = i & 127;
  float bn = gamma[c] * (out2[i] - mu[c]) * rsqrtf(var[c] + EPS_BN) + beta[c];
  xh[i] = (xh[i] + fmaxf(bn, 0.f)) * 0.5f;
}

// ---------------- misc small kernels ----------------
__global__ void copy_k(float* __restrict__ d, const float* __restrict__ s, int n){
  int i = blockIdx.x * 256 + threadIdx.x;
  if (i < n) d[i] = s[i];
}
// bout[j] = badd[j] + sum_k bin[k] * W[k*128 + j]
__global__ void bias_comb_k(const float* __restrict__ bin, const float* __restrict__ W,
                            const float* __restrict__ badd, float* __restrict__ bout){
  int j = threadIdx.x;
  float s = badd[j];
  for (int k = 0; k < HDIM; k++) s = fmaf(bin[k], W[(size_t)k * HDIM + j], s);
  bout[j] = s;
}

// ===========================================================================
extern "C" void kernel_launch(void* const* d_in, const int* in_sizes, int n_in,
                              void* d_out, int out_size, void* d_ws, size_t ws_size,
                              hipStream_t stream) {
  const float* x      = (const float*)d_in[0];
  const int*   ei     = (const int*)  d_in[1];
  const float* ea     = (const float*)d_in[2];
  const float* W_node = (const float*)d_in[3];
  const float* b_node = (const float*)d_in[4];
  const float* W_edge = (const float*)d_in[5];
  const float* b_edge = (const float*)d_in[6];
  const float* W_ee   = (const float*)d_in[7];
  const float* b_ee   = (const float*)d_in[8];
  const float* W_pre  = (const float*)d_in[9];
  const float* b_pre  = (const float*)d_in[10];
  const float* W_post = (const float*)d_in[11];
  const float* b_post = (const float*)d_in[12];
  const float* W_lin  = (const float*)d_in[13];
  const float* b_lin  = (const float*)d_in[14];
  const float* gamma  = (const float*)d_in[15];
  const float* beta   = (const float*)d_in[16];
  const float* We1    = (const float*)d_in[17];
  const float* be1    = (const float*)d_in[18];
  const float* We2    = (const float*)d_in[19];
  const float* be2    = (const float*)d_in[20];

  const int* src = ei;
  const int* dst = ei + EDGES;

  float* xh = (float*)d_out;
  float* e  = xh + (size_t)NODES * HDIM;

  // ---- workspace bump allocator (64B aligned regions) ----
  char* wp = (char*)d_ws;
  auto alloc = [&](size_t bytes) -> char* {
    char* r = wp;
    wp += (bytes + 63) & ~(size_t)63;
    return r;
  };
  float* h     = (float*)alloc((size_t)EDGES * HDIM * 4);
  float* agg   = (float*)alloc((size_t)NODES * 512 * 4);
  float* out2  = (float*)alloc((size_t)NODES * HDIM * 4);
  int*   cnt    = (int*)alloc(NODES * 4);
  int*   cursor = (int*)alloc(NODES * 4);
  int*   off    = (int*)alloc((NODES + 1) * 4);
  int*   eidx   = (int*)alloc(EDGES * 4);
  float* fdeg = (float*)alloc(NODES * 4);
  float* invf = (float*)alloc(NODES * 4);
  float* Wc1  = (float*)alloc(384 * HDIM * 4);     // [Wp1;Wp2;W_ee@Wp3]
  float* Wc2  = (float*)alloc(1664 * HDIM * 4);    // W_post@W_lin
  float* bc1  = (float*)alloc(HDIM * 4);
  float* bc2  = (float*)alloc(HDIM * 4);
  float* mu   = (float*)alloc(HDIM * 4);
  float* var  = (float*)alloc(HDIM * 4);
  auto allocS = [&](int K) -> unsigned short* { return (unsigned short*)alloc((size_t)K * HDIM * 2); };
  unsigned short* BpNh = allocS(64);   unsigned short* BpNl = allocS(64);
  unsigned short* BpEh = allocS(32);   unsigned short* BpEl = allocS(32);
  unsigned short* Bp1h = allocS(384);  unsigned short* Bp1l = allocS(384);
  unsigned short* Bp2h = allocS(1664); unsigned short* Bp2l = allocS(1664);
  unsigned short* Bp3h = allocS(384);  unsigned short* Bp3l = allocS(384);
  unsigned short* Bp4h = allocS(128);  unsigned short* Bp4l = allocS(128);

  dim3 blk(256);
  auto mgrid = [](int M){ return dim3(1, (M + 127) / 128); };
  auto bgrid = [](int K){ return dim3((K / 32) * 8); };

  GArgs g{};

  // ---- once-per-call prep: degrees + CSR over dst ----
  deg_init_k <<<(NODES + 255) / 256, blk, 0, stream>>>(cnt, cursor);
  deg_count_k<<<(EDGES + 255) / 256, blk, 0, stream>>>(dst, cnt);
  deg_fin_k  <<<(NODES + 255) / 256, blk, 0, stream>>>(cnt, fdeg, invf);
  scan_k     <<<1, blk, 0, stream>>>(cnt, off);
  csr_fill_k <<<(EDGES + 255) / 256, blk, 0, stream>>>(dst, off, cursor, eidx);

  bprep_k<<<bgrid(FDIM), 64, 0, stream>>>(W_node, BpNh, BpNl);
  bprep_k<<<bgrid(DDIM), 64, 0, stream>>>(W_edge, BpEh, BpEl);

  // xh = x @ W_node + b_node
  g = GArgs{}; g.A = x; g.Bph = BpNh; g.Bpl = BpNl; g.bias = b_node; g.C = xh;
  g.M = NODES; g.K = FDIM;
  mgemm_k<0,0><<<mgrid(NODES), blk, 0, stream>>>(g);

  // e = edge_attr @ W_edge + b_edge
  g = GArgs{}; g.A = ea; g.Bph = BpEh; g.Bpl = BpEl; g.bias = b_edge; g.C = e;
  g.M = EDGES; g.K = DDIM;
  mgemm_k<0,0><<<mgrid(EDGES), blk, 0, stream>>>(g);

  for (int l = 0; l < 2; l++){
    const float* W_ee_l   = W_ee   + (size_t)l * HDIM * HDIM;
    const float* b_ee_l   = b_ee   + l * HDIM;
    const float* W_pre_l  = W_pre  + (size_t)l * 3 * HDIM * HDIM;
    const float* b_pre_l  = b_pre  + l * HDIM;
    const float* W_post_l = W_post + (size_t)l * 13 * HDIM * HDIM;
    const float* b_post_l = b_post + l * HDIM;
    const float* W_lin_l  = W_lin  + (size_t)l * HDIM * HDIM;
    const float* b_lin_l  = b_lin  + l * HDIM;
    const float* gamma_l  = gamma  + l * HDIM;
    const float* beta_l   = beta   + l * HDIM;
    const float* We1_l    = We1    + (size_t)l * 3 * HDIM * HDIM;
    const float* be1_l    = be1    + l * HDIM;
    const float* We2_l    = We2    + (size_t)l * HDIM * HDIM;
    const float* be2_l    = be2    + l * HDIM;
    const float* Wp3      = W_pre_l + (size_t)2 * HDIM * HDIM;  // rows 256..383

    // Wc1 = [Wp1;Wp2 ; W_ee @ Wp3],  bc1 = b_pre + b_ee@Wp3
    copy_k<<<(2 * HDIM * HDIM + 255) / 256, blk, 0, stream>>>(Wc1, W_pre_l, 2 * HDIM * HDIM);
    g = GArgs{}; g.A = W_ee_l; g.B = Wp3; g.C = Wc1 + (size_t)2 * HDIM * HDIM;
    g.M = HDIM; g.K = HDIM;
    gemm_k<0,0><<<dim3(2, 2), blk, 0, stream>>>(g);
    bias_comb_k<<<1, HDIM, 0, stream>>>(b_ee_l, Wp3, b_pre_l, bc1);
    bprep_k<<<bgrid(3 * HDIM), 64, 0, stream>>>(Wc1, Bp1h, Bp1l);

    // h = [xh[dst], xh[src], e] @ Wc1 + bc1
    g = GArgs{}; g.A = e; g.s0 = xh; g.s1 = xh; g.i0 = dst; g.i1 = src;
    g.Bph = Bp1h; g.Bpl = Bp1l; g.bias = bc1; g.C = h; g.M = EDGES; g.K = 3 * HDIM;
    mgemm_k<1,0><<<mgrid(EDGES), blk, 0, stream>>>(g);

    // CSR multi-aggregation (fused finalize): agg = [mean|min|max|std]
    aggregate_k<<<(NODES + 1) / 2, blk, 0, stream>>>(h, off, eidx, agg);

    // Wc2 = W_post @ W_lin, bc2 = b_lin + b_post@W_lin
    g = GArgs{}; g.A = W_post_l; g.B = W_lin_l; g.C = Wc2; g.M = 13 * HDIM; g.K = HDIM;
    gemm_k<0,0><<<dim3(2, 26), blk, 0, stream>>>(g);
    bias_comb_k<<<1, HDIM, 0, stream>>>(b_post_l, W_lin_l, b_lin_l, bc2);
    bprep_k<<<bgrid(13 * HDIM), 64, 0, stream>>>(Wc2, Bp2h, Bp2l);

    // out2 = [xh, agg, agg*f, agg/f] @ Wc2 + bc2
    g = GArgs{}; g.A = xh; g.agg = agg; g.fs = fdeg; g.invfs = invf;
    g.Bph = Bp2h; g.Bpl = Bp2l; g.bias = bc2; g.C = out2; g.M = NODES; g.K = 13 * HDIM;
    mgemm_k<2,0><<<mgrid(NODES), blk, 0, stream>>>(g);

    // BN + residual relu
    bn_stats_k<<<HDIM, blk, 0, stream>>>(out2, mu, var);
    xh_update_k<<<(NODES * HDIM + 255) / 256, blk, 0, stream>>>(xh, out2, mu, var, gamma_l, beta_l);

    // t1 = relu([xh[src], xh[dst], e] @ We1 + be1)   (t1 reuses h)
    bprep_k<<<bgrid(3 * HDIM), 64, 0, stream>>>(We1_l, Bp3h, Bp3l);
    g = GArgs{}; g.A = e; g.s0 = xh; g.s1 = xh; g.i0 = src; g.i1 = dst;
    g.Bph = Bp3h; g.Bpl = Bp3l; g.bias = be1_l; g.C = h; g.M = EDGES; g.K = 3 * HDIM;
    mgemm_k<1,1><<<mgrid(EDGES), blk, 0, stream>>>(g);

    // e += 0.5 * (t1 @ We2 + be2)
    bprep_k<<<bgrid(HDIM), 64, 0, stream>>>(We2_l, Bp4h, Bp4l);
    g = GArgs{}; g.A = h; g.Bph = Bp4h; g.Bpl = Bp4l; g.bias = be2_l; g.C = e;
    g.M = EDGES; g.K = HDIM;
    mgemm_k<0,2><<<mgrid(EDGES), blk, 0, stream>>>(g);
  }
}